// Round 1
// 451.827 us; speedup vs baseline: 1.1622x; 1.1622x over previous
//
#include <hip/hip_runtime.h>

// PairwiseMLPLinkPredictor on MI355X (gfx950)
// feats = bf16(x[u]) * bf16(x[v]);  h1 = relu(feats@W1+b1);  h2 = relu(h1@W2+b2);
// out = h2@W3 + b3.
//
// R5: latency/serialization attack (from R4b @ 525us, mlp 388us):
//  - weights hoisted to registers ONCE (bv1+bv2 = 64 VGPR) -> no per-tile weight
//    loads, no vmcnt ordering constraint; gathers issued at TOP of iteration with
//    full GEMM1-span latency cover. VGPR ~128 -> 1 block/CU (16 waves).
//  - layer-3 atomics (8 atomicAdd/output, 125MB WRITE) replaced by LDS part[64][9]
//    cross-wave reduction + single coalesced store; init_out kernel deleted.
//  - h1 gets a dedicated LDS buffer -> 2 barriers/tile instead of 3.
//  - v_cvt_pk_bf16_f32 replaces software-RNE packing in staging + h1 writeback.
//  - cast_x + prep_w merged into one prologue launch.

typedef __attribute__((ext_vector_type(8))) short short8;   // 8 bf16 = 4 VGPRs
typedef __attribute__((ext_vector_type(4))) float floatx4;  // MFMA C/D frag
typedef __attribute__((ext_vector_type(4))) unsigned uintx4;
typedef __attribute__((ext_vector_type(2))) int intx2;

#define MT 64         // pairs per tile
#define NTHREADS 1024 // 16 waves
#define NBLOCKS 256   // 1 block/CU resident (LDS ~98KB, VGPR ~128)

__device__ __forceinline__ unsigned short f2bf(float f) {
  union { float f; unsigned u; } a; a.f = f;
  unsigned r = a.u + 0x7FFFu + ((a.u >> 16) & 1u);   // RNE
  return (unsigned short)(r >> 16);
}

// hw packed f32x2 -> bf16x2 (RNE), lo in low 16
__device__ __forceinline__ unsigned pkbf(float lo, float hi) {
  unsigned r;
  asm("v_cvt_pk_bf16_f32 %0, %1, %2" : "=v"(r) : "v"(lo), "v"(hi));
  return r;
}

// packed bf16x2 multiply via f32 unpack + hw repack
__device__ __forceinline__ unsigned bfmul2(unsigned ua, unsigned ub) {
  float lo = __uint_as_float(ua << 16)          * __uint_as_float(ub << 16);
  float hi = __uint_as_float(ua & 0xFFFF0000u) * __uint_as_float(ub & 0xFFFF0000u);
  return pkbf(lo, hi);
}

// ---------- prologue: x -> bf16 table; W1/W2 -> bf16 transposed [n][k] ----------
__global__ void prep_kernel(const float* __restrict__ x,
                            const float* __restrict__ W1,
                            const float* __restrict__ W2,
                            unsigned short* __restrict__ xb,
                            unsigned short* __restrict__ w1t,
                            unsigned short* __restrict__ w2t, int n4) {
  int i = blockIdx.x * blockDim.x + threadIdx.x;
  if (i < n4) {
    float4 v = ((const float4*)x)[i];
    ushort4 o;
    o.x = f2bf(v.x); o.y = f2bf(v.y); o.z = f2bf(v.z); o.w = f2bf(v.w);
    ((ushort4*)xb)[i] = o;
  } else {
    int j = i - n4;
    if (j < 256 * 256) {
      int k = j >> 8, n = j & 255;
      w1t[n * 256 + k] = f2bf(W1[k * 256 + n]);
    } else {
      j -= 256 * 256;
      if (j < 128 * 256) {
        int k = j >> 7, n = j & 127;
        w2t[n * 256 + k] = f2bf(W2[k * 128 + n]);
      }
    }
  }
}

// ---------- fused pairwise MLP, persistent, weights-in-registers ----------
__global__ __launch_bounds__(NTHREADS, 4) void mlp_kernel(
    const unsigned short* __restrict__ xb,
    const unsigned short* __restrict__ w1t,
    const unsigned short* __restrict__ w2t,
    const float* __restrict__ b1,
    const float* __restrict__ b2,
    const float* __restrict__ w3,
    const float* __restrict__ b3,
    const int* __restrict__ ep,
    float* __restrict__ out,
    int E)
{
  // feats double-buffer (2x32KB) + dedicated h1 buffer (32KB) + partials (2.25KB)
  // 16B chunks XOR-swizzled by (row & 15): conflict-free stride-512 ds_read_b128.
  __shared__ __align__(16) unsigned short feats[2][MT * 256];
  __shared__ __align__(16) unsigned short h1buf[MT * 256];
  __shared__ float part[MT][9];   // [row][ng2], padded to 9 to spread banks

  const int tid  = threadIdx.x;
  const int wv   = tid >> 6;      // 0..15
  const int lane = tid & 63;
  const int q    = lane >> 4;     // quad 0..3
  const int r16  = lane & 15;
  const int c    = tid & 31;      // 16B chunk within 512B row (staging)
  const int mr0  = tid >> 5;      // staging row base 0..31 (rows mr0, mr0+32)

  const int ntiles = (E + MT - 1) / MT;

  // GEMM1: wave owns 64 rows x 16 cols (n1); GEMM2: 32 rows x 16 cols (n2)
  const int n1  = wv * 16 + r16;
  const int mg2 = wv >> 3;        // 0..1
  const int ng2 = wv & 7;         // 0..7
  const int n2  = ng2 * 16 + r16;

  // ---- hoist loop-invariant weights into registers (32 + 32 VGPR) ----
  short8 bv1[8], bv2[8];
  {
    const unsigned short* const b1p = w1t + n1 * 256 + q * 8;
    const unsigned short* const b2p = w2t + n2 * 256 + q * 8;
    #pragma unroll
    for (int kt = 0; kt < 8; ++kt) {
      bv1[kt] = *(const short8*)(b1p + kt * 32);
      bv2[kt] = *(const short8*)(b2p + kt * 32);
    }
  }
  const float bias1 = b1[n1];
  const float bias2 = b2[n2];
  const float w3v   = w3[n2];
  const float b3v   = b3[0];

  // ---- prologue: stage tile t0 into feats[0]; preload ep for t0+NBLOCKS ----
  intx2 uv0, uv1;
  {
    const int t0 = blockIdx.x;
    #pragma unroll
    for (int s = 0; s < 2; ++s) {
      int m = mr0 + 32 * s;
      int g = t0 * MT + m; if (g >= E) g = E - 1;
      intx2 uv = __builtin_nontemporal_load((const intx2*)(ep + 2 * (size_t)g));
      uintx4 a = *(const uintx4*)(xb + ((size_t)(unsigned)uv.x << 8) + (c << 3));
      uintx4 b = *(const uintx4*)(xb + ((size_t)(unsigned)uv.y << 8) + (c << 3));
      uintx4 pv;
      #pragma unroll
      for (int tt = 0; tt < 4; ++tt) pv[tt] = bfmul2(a[tt], b[tt]);
      *(uintx4*)((char*)feats[0] + m * 512 + ((c ^ (m & 15)) << 4)) = pv;
    }
    int t1 = t0 + NBLOCKS;
    int g0 = t1 * MT + mr0;      if (g0 >= E) g0 = E - 1;
    int g1 = t1 * MT + mr0 + 32; if (g1 >= E) g1 = E - 1;
    uv0 = __builtin_nontemporal_load((const intx2*)(ep + 2 * (size_t)g0));
    uv1 = __builtin_nontemporal_load((const intx2*)(ep + 2 * (size_t)g1));
  }
  __syncthreads();

  int fp = 0;
  for (int t = blockIdx.x; t < ntiles; t += NBLOCKS) {
    // ---- (1) issue next-tile gather loads FIRST (no VMEM after them until
    //      the barrier drain right before their use). Plain loads: let L2 cache xb.
    uintx4 ra0 = *(const uintx4*)(xb + ((size_t)(unsigned)uv0.x << 8) + (c << 3));
    uintx4 rb0 = *(const uintx4*)(xb + ((size_t)(unsigned)uv0.y << 8) + (c << 3));
    uintx4 ra1 = *(const uintx4*)(xb + ((size_t)(unsigned)uv1.x << 8) + (c << 3));
    uintx4 rb1 = *(const uintx4*)(xb + ((size_t)(unsigned)uv1.y << 8) + (c << 3));

    // ---- (2) prefetch ep indices for tile t+2*NBLOCKS ----
    intx2 nv0, nv1;
    {
      int t2 = t + 2 * NBLOCKS;
      int g0 = t2 * MT + mr0;      if (g0 >= E) g0 = E - 1;
      int g1 = t2 * MT + mr0 + 32; if (g1 >= E) g1 = E - 1;
      nv0 = __builtin_nontemporal_load((const intx2*)(ep + 2 * (size_t)g0));
      nv1 = __builtin_nontemporal_load((const intx2*)(ep + 2 * (size_t)g1));
    }

    // ---- (3) GEMM1: feats[fp] (LDS) x bv1 (regs), no global loads ----
    floatx4 acc[4];
    #pragma unroll
    for (int i = 0; i < 4; ++i) acc[i] = (floatx4){0.f, 0.f, 0.f, 0.f};

    const char* const a1base = (const char*)feats[fp] + r16 * 512;
    #pragma unroll
    for (int kt = 0; kt < 8; ++kt) {
      const int aoff = (kt << 6) ^ ((q ^ r16) << 4);
      short8 av[4];
      #pragma unroll
      for (int mt = 0; mt < 4; ++mt)
        av[mt] = *(const short8*)(a1base + mt * (16 * 512) + aoff);
      #pragma unroll
      for (int mt = 0; mt < 4; ++mt)
        acc[mt] = __builtin_amdgcn_mfma_f32_16x16x32_bf16(av[mt], bv1[kt], acc[mt], 0, 0, 0);
    }

    // ---- (4) h1 writeback (bias+relu, packed bf16 cvt) into h1buf, swizzled ----
    // safe: GEMM2(t-1) finished reading h1buf before barrier#2(t-1).
    {
      char* const hb = (char*)h1buf;
      const int chb = n1 >> 3;
      const int eo  = (n1 & 7) << 1;
      #pragma unroll
      for (int mt = 0; mt < 4; ++mt) {
        #pragma unroll
        for (int rp = 0; rp < 2; ++rp) {
          float h0 = fmaxf(acc[mt][2 * rp]     + bias1, 0.f);
          float h1 = fmaxf(acc[mt][2 * rp + 1] + bias1, 0.f);
          unsigned pk = pkbf(h0, h1);
          int m0 = mt * 16 + q * 4 + 2 * rp;
          *(unsigned short*)(hb + m0 * 512 + ((chb ^ (m0 & 15)) << 4) + eo) =
              (unsigned short)pk;
          *(unsigned short*)(hb + (m0 + 1) * 512 + ((chb ^ ((m0 + 1) & 15)) << 4) + eo) =
              (unsigned short)(pk >> 16);
        }
      }
    }
    __syncthreads();   // barrier #1: h1 ready; feats[fp] reads done; gathers drained

    // ---- (5) convert + store staged feats for tile t+NBLOCKS into feats[fp^1] ----
    // feats[fp^1] dead since GEMM1(t-1). Consuming ra/rb here keeps their live
    // range to the GEMM1 span (register pressure) with full GEMM1 latency cover.
    {
      char* const bufn = (char*)feats[fp ^ 1];
      uintx4 pv0, pv1;
      #pragma unroll
      for (int tt = 0; tt < 4; ++tt) pv0[tt] = bfmul2(ra0[tt], rb0[tt]);
      #pragma unroll
      for (int tt = 0; tt < 4; ++tt) pv1[tt] = bfmul2(ra1[tt], rb1[tt]);
      const int m0 = mr0, m1 = mr0 + 32;
      *(uintx4*)(bufn + m0 * 512 + ((c ^ (m0 & 15)) << 4)) = pv0;
      *(uintx4*)(bufn + m1 * 512 + ((c ^ (m1 & 15)) << 4)) = pv1;
    }

    // ---- (6) GEMM2: h1buf (LDS) x bv2 (regs); K=256 ----
    floatx4 acc2[2];
    acc2[0] = (floatx4){0.f, 0.f, 0.f, 0.f};
    acc2[1] = (floatx4){0.f, 0.f, 0.f, 0.f};
    const char* const a2base = (const char*)h1buf + (mg2 * 32 + r16) * 512;
    #pragma unroll
    for (int kt = 0; kt < 8; ++kt) {
      const int aoff = (kt << 6) ^ ((q ^ r16) << 4);
      short8 av0 = *(const short8*)(a2base + aoff);
      short8 av1 = *(const short8*)(a2base + 16 * 512 + aoff);
      acc2[0] = __builtin_amdgcn_mfma_f32_16x16x32_bf16(av0, bv2[kt], acc2[0], 0, 0, 0);
      acc2[1] = __builtin_amdgcn_mfma_f32_16x16x32_bf16(av1, bv2[kt], acc2[1], 0, 0, 0);
    }

    // ---- (7) layer 3 partials -> LDS (replaces 8x atomicAdd per output) ----
    {
      #pragma unroll
      for (int mt = 0; mt < 2; ++mt) {
        #pragma unroll
        for (int r = 0; r < 4; ++r) {
          float h = fmaxf(acc2[mt][r] + bias2, 0.f);
          float pp = h * w3v;
          pp += __shfl_xor(pp, 1);
          pp += __shfl_xor(pp, 2);
          pp += __shfl_xor(pp, 4);
          pp += __shfl_xor(pp, 8);
          if (r16 == 0)
            part[mg2 * 32 + mt * 16 + q * 4 + r][ng2] = pp;
        }
      }
    }
    __syncthreads();   // barrier #2: feats(t+NB) staged; partials ready; h1buf reusable

    // ---- (8) final reduce + single coalesced store (wave 0) ----
    if (tid < MT) {
      int g = t * MT + tid;
      if (g < E) {
        float s = (part[tid][0] + part[tid][1]) + (part[tid][2] + part[tid][3]) +
                  (part[tid][4] + part[tid][5]) + (part[tid][6] + part[tid][7]);
        out[g] = s + b3v;
      }
    }

    fp ^= 1;
    uv0 = nv0; uv1 = nv1;
  }
}

extern "C" void kernel_launch(void* const* d_in, const int* in_sizes, int n_in,
                              void* d_out, int out_size, void* d_ws, size_t ws_size,
                              hipStream_t stream) {
  const float* x  = (const float*)d_in[0];
  const float* W1 = (const float*)d_in[1];
  const float* b1 = (const float*)d_in[2];
  const float* W2 = (const float*)d_in[3];
  const float* b2 = (const float*)d_in[4];
  const float* W3 = (const float*)d_in[5];
  const float* b3 = (const float*)d_in[6];
  // d_in[7] = edge_index (unused by the reference computation)
  const int*   ep = (const int*)d_in[8];
  float* out = (float*)d_out;

  const int NX = in_sizes[0];        // 100000*256 = 25,600,000
  const int E  = in_sizes[8] / 2;    // 1,000,000

  // workspace layout: xb (NX bf16) | w1t (256*256 bf16) | w2t (128*256 bf16)
  unsigned short* xb  = (unsigned short*)d_ws;
  unsigned short* w1t = (unsigned short*)((char*)d_ws + (size_t)NX * 2);
  unsigned short* w2t = w1t + 256 * 256;

  const int n4 = NX / 4;
  const int prep_threads = n4 + 256 * 256 + 128 * 256;
  prep_kernel<<<(prep_threads + 255) / 256, 256, 0, stream>>>(x, W1, W2, xb, w1t, w2t, n4);
  mlp_kernel<<<NBLOCKS, NTHREADS, 0, stream>>>(xb, w1t, w2t, b1, b2, W3, b3, ep, out, E);
}